// Round 3
// baseline (60.292 us; speedup 1.0000x reference)
//
#include <hip/hip_runtime.h>

// BaseGraph (NRI node2edge/edge2node) on the complete graph minus diagonal,
// normalize-by-N. Closed form (receivers/senders = np.where(ones - eye)):
//   out[b,n,0:D]   = (N-1)/N * x[b,n,:]
//   out[b,n,D:2D]  = (sum_j x[b,j,:] - x[b,n,:]) / N
// O(B*N*D) instead of O(B*E*D); index arrays unused at runtime.
//
// R2 -> R3: fused to ONE dispatch. x is 1 MiB (L2-resident), so each block
// redundantly computes its batch's full feature sum (128 KB of L1/L2 reads,
// ~free), LDS-reduces 8 chunk partials, then streams its 16 output rows.
// No workspace, no atomics, no inter-kernel dependency.

constexpr int BATCH = 8;
constexpr int NNODE = 256;
constexpr int DFEAT = 128;          // 32 float4 per row
constexpr int V4 = DFEAT / 4;       // 32
constexpr int BPB = 16;             // blocks per batch -> 128 blocks total
constexpr int RPB = NNODE / BPB;    // 16 rows per block

__device__ __forceinline__ float4 f4add(float4 a, float4 b) {
  return make_float4(a.x + b.x, a.y + b.y, a.z + b.z, a.w + b.w);
}

__global__ void __launch_bounds__(256) basegraph_fused_kernel(
    const float* __restrict__ x, float* __restrict__ out) {
  const int b = blockIdx.x >> 4;        // BPB == 16
  const int rb = blockIdx.x & (BPB - 1);
  const int tid = threadIdx.x;
  const int dv = tid & (V4 - 1);        // float4 lane within row, 0..31
  const int c = tid >> 5;               // node-chunk, 0..7

  __shared__ float4 Sp[8][V4];          // chunk partials, 4 KB
  __shared__ float4 S[V4];              // batch feature sum, 512 B

  const float4* xb = reinterpret_cast<const float4*>(x) + (size_t)b * NNODE * V4;

  // Phase 1: thread sums 32 nodes (chunk c) at float4-lane dv.
  const float4* p = xb + (size_t)(c * 32) * V4 + dv;
  float4 acc = p[0];
#pragma unroll
  for (int i = 1; i < 32; ++i) acc = f4add(acc, p[(size_t)i * V4]);
  Sp[c][dv] = acc;
  __syncthreads();

  if (tid < V4) {
    float4 s = Sp[0][tid];
#pragma unroll
    for (int c2 = 1; c2 < 8; ++c2) s = f4add(s, Sp[c2][tid]);
    S[tid] = s;
  }
  __syncthreads();

  // Phase 2: stream RPB rows; 256 threads cover 8 rows x 32 float4 per pass.
  constexpr float kRecvScale = (float)(NNODE - 1) / (float)NNODE;  // 255/256
  constexpr float kInvN = 1.0f / (float)NNODE;
  const float4 s4 = S[dv];

#pragma unroll
  for (int pass = 0; pass < RPB / 8; ++pass) {
    const int r = rb * RPB + pass * 8 + c;
    const float4 x4 = xb[(size_t)r * V4 + dv];
    float4 h1, h2;
    h1.x = x4.x * kRecvScale;
    h1.y = x4.y * kRecvScale;
    h1.z = x4.z * kRecvScale;
    h1.w = x4.w * kRecvScale;
    h2.x = (s4.x - x4.x) * kInvN;
    h2.y = (s4.y - x4.y) * kInvN;
    h2.z = (s4.z - x4.z) * kInvN;
    h2.w = (s4.w - x4.w) * kInvN;
    float4* orow =
        reinterpret_cast<float4*>(out) + ((size_t)(b * NNODE + r)) * (2 * V4);
    orow[dv] = h1;             // first half: receiver self-features
    orow[V4 + dv] = h2;        // second half: summed sender features
  }
}

extern "C" void kernel_launch(void* const* d_in, const int* in_sizes, int n_in,
                              void* d_out, int out_size, void* d_ws,
                              size_t ws_size, hipStream_t stream) {
  const float* x = (const float*)d_in[0];
  // d_in[1] (receivers) / d_in[2] (senders): fixed complete graph; unused.
  float* out = (float*)d_out;
  basegraph_fused_kernel<<<BATCH * BPB, 256, 0, stream>>>(x, out);
}

// Round 4
// 59.547 us; speedup vs baseline: 1.0125x; 1.0125x over previous
//
#include <hip/hip_runtime.h>

// BaseGraph (NRI node2edge/edge2node) on the complete graph minus diagonal,
// normalize-by-N. Closed form (receivers/senders = np.where(ones - eye)):
//   out[b,n,0:D]   = (N-1)/N * x[b,n,:]
//   out[b,n,D:2D]  = (sum_j x[b,j,:] - x[b,n,:]) / N
// O(B*N*D) instead of O(B*E*D); index arrays unused at runtime.
//
// R3 -> R4: fusion regressed (60.3 vs R2's 58.8) — 128 blocks left half the
// CUs idle and serialized a 128KB read chain per block behind a barrier.
// Reverting to the two-kernel shape; kernel 1 now 128 blocks with a 16-deep
// chain (was 64 blocks / 32-deep). Kernel 2 folds 16 L1-hot partials.

constexpr int BATCH = 8;
constexpr int NNODE = 256;
constexpr int DFEAT = 128;
constexpr int CHUNKS = 16;                 // node chunks per batch
constexpr int NPC = NNODE / CHUNKS;        // 16 nodes per chunk

// Kernel 1: P[b][c][d] = sum over nodes in chunk c of x[b][n][d].
// grid = BATCH*CHUNKS (128), block = DFEAT (128). No atomics, no init.
__global__ void __launch_bounds__(DFEAT) partial_sum_kernel(
    const float* __restrict__ x, float* __restrict__ P) {
  const int b = blockIdx.x >> 4;           // CHUNKS == 16
  const int c = blockIdx.x & (CHUNKS - 1);
  const int d = threadIdx.x;
  const float* xb = x + ((size_t)(b * NNODE + c * NPC)) * DFEAT + d;
  float acc = 0.0f;
#pragma unroll
  for (int i = 0; i < NPC; ++i) {
    acc += xb[(size_t)i * DFEAT];
  }
  P[(b * CHUNKS + c) * DFEAT + d] = acc;
}

// Kernel 2: one thread per float4 of x. Folds the CHUNKS partials into the
// batch sum, then writes both output halves. out layout: [B, N, 2*D].
__global__ void __launch_bounds__(256) edge2node_kernel(
    const float* __restrict__ x, const float* __restrict__ P,
    float* __restrict__ out) {
  const int tid = blockIdx.x * 256 + threadIdx.x;  // 0 .. B*N*D/4 - 1
  const int dv = tid & (DFEAT / 4 - 1);            // float4 index within row
  const int bn = tid >> 5;                         // DFEAT/4 == 32
  const int b = bn >> 8;                           // NNODE == 256

  const float4 x4 = reinterpret_cast<const float4*>(x)[tid];

  // Fold 16 partial float4s (hot in L1: 8 KB per batch).
  const float4* Pb =
      reinterpret_cast<const float4*>(P) + b * (CHUNKS * DFEAT / 4) + dv;
  float4 s4 = Pb[0];
#pragma unroll
  for (int c = 1; c < CHUNKS; ++c) {
    const float4 p = Pb[c * (DFEAT / 4)];
    s4.x += p.x;
    s4.y += p.y;
    s4.z += p.z;
    s4.w += p.w;
  }

  constexpr float kRecvScale = (float)(NNODE - 1) / (float)NNODE;  // 255/256
  constexpr float kInvN = 1.0f / (float)NNODE;

  float4 h1, h2;
  h1.x = x4.x * kRecvScale;
  h1.y = x4.y * kRecvScale;
  h1.z = x4.z * kRecvScale;
  h1.w = x4.w * kRecvScale;
  h2.x = (s4.x - x4.x) * kInvN;
  h2.y = (s4.y - x4.y) * kInvN;
  h2.z = (s4.z - x4.z) * kInvN;
  h2.w = (s4.w - x4.w) * kInvN;

  float4* orow = reinterpret_cast<float4*>(out + (size_t)bn * (2 * DFEAT));
  orow[dv] = h1;                  // first half: receiver self-features
  orow[DFEAT / 4 + dv] = h2;      // second half: summed sender features
}

extern "C" void kernel_launch(void* const* d_in, const int* in_sizes, int n_in,
                              void* d_out, int out_size, void* d_ws,
                              size_t ws_size, hipStream_t stream) {
  const float* x = (const float*)d_in[0];
  // d_in[1] (receivers) / d_in[2] (senders): fixed complete graph; unused.
  float* P = (float*)d_ws;        // BATCH * CHUNKS * DFEAT floats = 64 KB
  float* out = (float*)d_out;

  partial_sum_kernel<<<BATCH * CHUNKS, DFEAT, 0, stream>>>(x, P);

  const int total_vec4 = BATCH * NNODE * DFEAT / 4;  // 65536
  edge2node_kernel<<<total_vec4 / 256, 256, 0, stream>>>(x, P, out);
}